// Round 1
// baseline (228.349 us; speedup 1.0000x reference)
//
#include <hip/hip_runtime.h>

// out[i] = [x2, x3, -(k1*x0 + k2*(x0-x1)), k2*(x0-x1)] per row of x (B,4).
// Pure streaming, touch-once: 128 MiB read + 128 MiB write, no reuse.
// v2: 4 rows per thread at stride blockDim -> 4 independent nontemporal
// loads in flight per thread (4-deep MLP) while keeping every memory
// instruction perfectly coalesced (lane i touches base+i, 16 B/lane).

typedef float f32x4 __attribute__((ext_vector_type(4)));

#define ROWS_PER_THREAD 4
#define BLOCK 256

__global__ __launch_bounds__(BLOCK) void lagrangian_ode_kernel(
    const f32x4* __restrict__ x,
    const float* __restrict__ k1p,
    const float* __restrict__ k2p,
    f32x4* __restrict__ out,
    int n_rows) {
    const float k1 = k1p[0];   // uniform -> s_load
    const float k2 = k2p[0];
    const int base = blockIdx.x * (BLOCK * ROWS_PER_THREAD) + threadIdx.x;

    f32x4 v[ROWS_PER_THREAD];
    int idx[ROWS_PER_THREAD];

    // Issue all loads first: 4 independent global_load_dwordx4 in flight.
#pragma unroll
    for (int r = 0; r < ROWS_PER_THREAD; ++r) {
        idx[r] = base + r * BLOCK;
        if (idx[r] < n_rows) {
            v[r] = __builtin_nontemporal_load(&x[idx[r]]);
        }
    }

    // Compute + store (trivial VALU: 1 sub, 2 mul/fma, 1 neg per row).
#pragma unroll
    for (int r = 0; r < ROWS_PER_THREAD; ++r) {
        if (idx[r] < n_rows) {
            const float d = v[r].x - v[r].y;   // q0 - q1
            f32x4 o;
            o.x = v[r].z;                      // qd0
            o.y = v[r].w;                      // qd1
            o.z = -(k1 * v[r].x + k2 * d);     // qdd0
            o.w = k2 * d;                      // qdd1
            __builtin_nontemporal_store(o, &out[idx[r]]);
        }
    }
}

extern "C" void kernel_launch(void* const* d_in, const int* in_sizes, int n_in,
                              void* d_out, int out_size, void* d_ws, size_t ws_size,
                              hipStream_t stream) {
    // setup_inputs order: t (1), x (B*4), k1 (1), k2 (1)
    const f32x4* x  = (const f32x4*)d_in[1];
    const float* k1 = (const float*)d_in[2];
    const float* k2 = (const float*)d_in[3];
    f32x4* out = (f32x4*)d_out;

    int n_rows = in_sizes[1] / 4;   // B = 8388608
    int rows_per_block = BLOCK * ROWS_PER_THREAD;           // 1024
    int grid = (n_rows + rows_per_block - 1) / rows_per_block;  // 8192
    lagrangian_ode_kernel<<<grid, BLOCK, 0, stream>>>(x, k1, k2, out, n_rows);
}